// Round 2
// baseline (1224.943 us; speedup 1.0000x reference)
//
#include <hip/hip_runtime.h>

#define MAXD 192
#define NCH  16
#define CG   4            // channels staged per barrier group
#define NG   4            // NCH / CG

__global__ __launch_bounds__(256, 4) void pbm_kernel(
    const float* __restrict__ lfeat,   // (16,1,16,H,W)
    const float* __restrict__ rfeat,
    const float* __restrict__ points,  // (1,N,2)
    const int* __restrict__ pW, const int* __restrict__ pH,
    float* __restrict__ out)           // (1,N,192,8)
{
    const int W = *pW, H = *pH;
    const int HW = W * H;
    const int n   = blockIdx.x;
    const int j   = blockIdx.y;
    const int tid = threadIdx.x;

    const float px  = points[2 * n];
    const float py  = points[2 * n + 1];
    const float pxf = floorf(px), pyf = floorf(py);
    const float fx  = px - pxf;
    const float fy  = py - pyf;
    const int   x0i = (int)pxf;
    const int   y0i = (int)pyf;

    __shared__ float sv[CG][5][256];   // right strip, kk = tid
    __shared__ float sl[CG][5][8];     // left 5x5 windows (padded rows)
    __shared__ float part4[4][48];
    __shared__ float val4[48];

    const int wv = tid >> 6;           // wave id 0..3
    const int dl = tid & 63;

    float acc4 = 0.0f;                 // pass0: disparity dl (<48), channels wv,wv+4,..
    float acc1 = 0.0f;                 // pass1: disparity tid (<192), all channels

    // =============== PASS 0: scale 4, D=48, level j+8 ===============
    {
        const int S = 4, D = 48;
        const int lvl = j + 8;

        // hoisted per-thread column constants (kk = tid)
        const int   cx  = x0i + S * tid - S * (D + 1);
        const int   cb0 = min(max(cx, 0), W - 1);
        const int   cb1 = min(max(cx + 1, 0), W - 1);
        const float mx0 = ((unsigned)cx       < (unsigned)W) ? 1.0f : 0.0f;
        const float mx1 = ((unsigned)(cx + 1) < (unsigned)W) ? 1.0f : 0.0f;
        const bool  strip = tid < (D + 4);

        float wy0[5], wy1[5]; int yb0[5], yb1[5];
#pragma unroll
        for (int yy = 0; yy < 5; ++yy) {
            int yr = y0i + S * (yy - 2);
            wy0[yy] = ((unsigned)yr       < (unsigned)H) ? (1.0f - fy) : 0.0f;
            wy1[yy] = ((unsigned)(yr + 1) < (unsigned)H) ? fy          : 0.0f;
            yb0[yy] = min(max(yr, 0), H - 1) * W;
            yb1[yy] = min(max(yr + 1, 0), H - 1) * W;
        }

        // left-window decomposition (group-independent)
        const bool lw = tid < CG * 25;
        int lcc = 0, lyy = 0, lxx = 0, la0 = 0, la1 = 0, lb0 = 0, lb1 = 0;
        float lmx0 = 0, lmx1 = 0, lwy0 = 0, lwy1 = 0;
        if (lw) {
            lcc = tid / 25;
            int w = tid - lcc * 25;
            lyy = w / 5;
            lxx = w - lyy * 5;
            int lx = x0i + S * (lxx - 2);
            int ly = y0i + S * (lyy - 2);
            la0 = min(max(lx, 0), W - 1);
            la1 = min(max(lx + 1, 0), W - 1);
            lb0 = min(max(ly, 0), H - 1) * W;
            lb1 = min(max(ly + 1, 0), H - 1) * W;
            lmx0 = ((unsigned)lx       < (unsigned)W) ? 1.f : 0.f;
            lmx1 = ((unsigned)(lx + 1) < (unsigned)W) ? 1.f : 0.f;
            lwy0 = ((unsigned)ly       < (unsigned)H) ? (1.f - fy) : 0.f;
            lwy1 = ((unsigned)(ly + 1) < (unsigned)H) ? fy : 0.f;
        }

        for (int q = 0; q < NG; ++q) {
            const float* Rq = rfeat + (size_t)(lvl * NCH + 4 * q) * HW;
            const float* Lq = lfeat + (size_t)(lvl * NCH + 4 * q) * HW;
            if (strip) {
#pragma unroll
                for (int cc = 0; cc < CG; ++cc) {
                    const float* Rp = Rq + (size_t)cc * HW;
#pragma unroll
                    for (int yy = 0; yy < 5; ++yy) {
                        float v00 = Rp[yb0[yy] + cb0] * mx0, v01 = Rp[yb0[yy] + cb1] * mx1;
                        float v10 = Rp[yb1[yy] + cb0] * mx0, v11 = Rp[yb1[yy] + cb1] * mx1;
                        float top = v00 + fx * (v01 - v00);
                        float bot = v10 + fx * (v11 - v10);
                        sv[cc][yy][tid] = top * wy0[yy] + bot * wy1[yy];
                    }
                }
            }
            if (lw) {
                const float* Lp = Lq + (size_t)lcc * HW;
                float v00 = Lp[lb0 + la0] * lmx0, v01 = Lp[lb0 + la1] * lmx1;
                float v10 = Lp[lb1 + la0] * lmx0, v11 = Lp[lb1 + la1] * lmx1;
                float top = v00 + fx * (v01 - v00);
                float bot = v10 + fx * (v11 - v10);
                sl[lcc][lyy][lxx] = top * lwy0 + bot * lwy1;
            }
            __syncthreads();
            if (dl < 48) {
                const int base = 47 - dl;
#pragma unroll
                for (int yy = 0; yy < 5; ++yy) {
                    const float* svp = &sv[wv][yy][base];
                    const float* slp = &sl[wv][yy][0];
                    acc4 += fabsf(slp[0] - svp[0]);
                    acc4 += fabsf(slp[1] - svp[1]);
                    acc4 += fabsf(slp[2] - svp[2]);
                    acc4 += fabsf(slp[3] - svp[3]);
                    acc4 += fabsf(slp[4] - svp[4]);
                }
            }
            __syncthreads();
        }
        if (dl < 48) part4[wv][dl] = acc4;
        __syncthreads();
        if (tid < 48) {
            float s4 = part4[0][tid] + part4[1][tid] + part4[2][tid] + part4[3][tid];
            val4[tid] = 1.0f - expf(-s4 * (1.0f / 400.0f));
        }
        // pass1 barriers make val4 visible before the epilogue; sv/sl reuse is safe.
    }

    // =============== PASS 1: scale 1, D=192, level j ===============
    {
        const int S = 1, D = 192;
        const int lvl = j;

        const int   cx  = x0i + tid - (D + 1);
        const int   cb0 = min(max(cx, 0), W - 1);
        const int   cb1 = min(max(cx + 1, 0), W - 1);
        const float mx0 = ((unsigned)cx       < (unsigned)W) ? 1.0f : 0.0f;
        const float mx1 = ((unsigned)(cx + 1) < (unsigned)W) ? 1.0f : 0.0f;
        const bool  strip = tid < (D + 4);

        float wy0[5], wy1[5]; int yb0[5], yb1[5];
#pragma unroll
        for (int yy = 0; yy < 5; ++yy) {
            int yr = y0i + S * (yy - 2);
            wy0[yy] = ((unsigned)yr       < (unsigned)H) ? (1.0f - fy) : 0.0f;
            wy1[yy] = ((unsigned)(yr + 1) < (unsigned)H) ? fy          : 0.0f;
            yb0[yy] = min(max(yr, 0), H - 1) * W;
            yb1[yy] = min(max(yr + 1, 0), H - 1) * W;
        }

        const bool lw = tid < CG * 25;
        int lcc = 0, lyy = 0, lxx = 0, la0 = 0, la1 = 0, lb0 = 0, lb1 = 0;
        float lmx0 = 0, lmx1 = 0, lwy0 = 0, lwy1 = 0;
        if (lw) {
            lcc = tid / 25;
            int w = tid - lcc * 25;
            lyy = w / 5;
            lxx = w - lyy * 5;
            int lx = x0i + S * (lxx - 2);
            int ly = y0i + S * (lyy - 2);
            la0 = min(max(lx, 0), W - 1);
            la1 = min(max(lx + 1, 0), W - 1);
            lb0 = min(max(ly, 0), H - 1) * W;
            lb1 = min(max(ly + 1, 0), H - 1) * W;
            lmx0 = ((unsigned)lx       < (unsigned)W) ? 1.f : 0.f;
            lmx1 = ((unsigned)(lx + 1) < (unsigned)W) ? 1.f : 0.f;
            lwy0 = ((unsigned)ly       < (unsigned)H) ? (1.f - fy) : 0.f;
            lwy1 = ((unsigned)(ly + 1) < (unsigned)H) ? fy : 0.f;
        }

        for (int q = 0; q < NG; ++q) {
            const float* Rq = rfeat + (size_t)(lvl * NCH + 4 * q) * HW;
            const float* Lq = lfeat + (size_t)(lvl * NCH + 4 * q) * HW;
            if (strip) {
#pragma unroll
                for (int cc = 0; cc < CG; ++cc) {
                    const float* Rp = Rq + (size_t)cc * HW;
#pragma unroll
                    for (int yy = 0; yy < 5; ++yy) {
                        float v00 = Rp[yb0[yy] + cb0] * mx0, v01 = Rp[yb0[yy] + cb1] * mx1;
                        float v10 = Rp[yb1[yy] + cb0] * mx0, v11 = Rp[yb1[yy] + cb1] * mx1;
                        float top = v00 + fx * (v01 - v00);
                        float bot = v10 + fx * (v11 - v10);
                        sv[cc][yy][tid] = top * wy0[yy] + bot * wy1[yy];
                    }
                }
            }
            if (lw) {
                const float* Lp = Lq + (size_t)lcc * HW;
                float v00 = Lp[lb0 + la0] * lmx0, v01 = Lp[lb0 + la1] * lmx1;
                float v10 = Lp[lb1 + la0] * lmx0, v11 = Lp[lb1 + la1] * lmx1;
                float top = v00 + fx * (v01 - v00);
                float bot = v10 + fx * (v11 - v10);
                sl[lcc][lyy][lxx] = top * lwy0 + bot * lwy1;
            }
            __syncthreads();
            if (tid < 192) {
                const int base = 191 - tid;
#pragma unroll
                for (int cc = 0; cc < CG; ++cc) {
#pragma unroll
                    for (int yy = 0; yy < 5; ++yy) {
                        const float* svp = &sv[cc][yy][base];
                        const float* slp = &sl[cc][yy][0];
                        acc1 += fabsf(slp[0] - svp[0]);
                        acc1 += fabsf(slp[1] - svp[1]);
                        acc1 += fabsf(slp[2] - svp[2]);
                        acc1 += fabsf(slp[3] - svp[3]);
                        acc1 += fabsf(slp[4] - svp[4]);
                    }
                }
            }
            __syncthreads();
        }
    }

    // =============== epilogue: upsample 48->192 and write ===============
    if (tid < MAXD) {
        float v1  = 1.0f - expf(-acc1 * (1.0f / 400.0f));
        float pos = (float)tid * (47.0f / 191.0f);
        float i0f = floorf(pos);
        int   i0  = (int)i0f;
        float w   = pos - i0f;
        int   i1  = min(i0 + 1, 47);
        float up  = val4[i0] + w * (val4[i1] - val4[i0]);
        out[((size_t)n * MAXD + tid) * 8 + j] = v1 + up;
    }
}

extern "C" void kernel_launch(void* const* d_in, const int* in_sizes, int n_in,
                              void* d_out, int out_size, void* d_ws, size_t ws_size,
                              hipStream_t stream) {
    const float* lf  = (const float*)d_in[0];
    const float* rf  = (const float*)d_in[1];
    const float* pts = (const float*)d_in[2];
    const int*   pW  = (const int*)d_in[3];
    const int*   pH  = (const int*)d_in[4];
    float* out = (float*)d_out;

    const int N = in_sizes[2] / 2;   // (B=1, N, 2)
    dim3 grid(N, 8, 1);
    pbm_kernel<<<grid, 256, 0, stream>>>(lf, rf, pts, pW, pH, out);
}

// Round 3
// 556.355 us; speedup vs baseline: 2.2017x; 2.2017x over previous
//
#include <hip/hip_runtime.h>

#define MAXD 192
#define NCH  16

// One block per (point n, output level j in 0..7).
// pass 0: level j+8 (scale 4, D=48, 4 channels per barrier group);
// pass 1: level j   (scale 1, D=192, 2 channels per barrier group).
// Key invariant: all sample coords are p + s*integer, so bilinear fractional
// weights (fx,fy) and validity masks depend only on the block -> hoisted.
__global__ __launch_bounds__(256) void pbm_kernel(
    const float* __restrict__ lfeat,   // (16,1,16,H,W)
    const float* __restrict__ rfeat,
    const float* __restrict__ points,  // (1,N,2)
    const int* __restrict__ pW, const int* __restrict__ pH,
    float* __restrict__ out)           // (1,N,192,8)
{
    const int W = *pW, H = *pH;
    const int HW = W * H;
    const int n   = blockIdx.x;
    const int j   = blockIdx.y;
    const int tid = threadIdx.x;

    const float px  = points[2 * n];
    const float py  = points[2 * n + 1];
    const float pxf = floorf(px), pyf = floorf(py);
    const float fx  = px - pxf;
    const float fy  = py - pyf;
    const int   x0i = (int)pxf;
    const int   y0i = (int)pyf;

    // svbuf overlays: pass0 uses [4][5][56] (1120 f), pass1 uses [2][5][200] (2000 f)
    __shared__ float svbuf[2000];
    __shared__ float slbuf[4 * 5 * 8];     // left windows [cc][yy][xx pad 8]
    __shared__ float part4[4][48];
    __shared__ float val4[48];

    const int wv = tid >> 6;               // wave 0..3
    const int dl = tid & 63;

    float acc1 = 0.0f;

    // =============== PASS 0: scale 4, D=48, level j+8, CG=4 ===============
    {
        const int lvl = j + 8;
        const int cx  = x0i + 4 * tid - 4 * 49;
        const int cb0 = min(max(cx, 0), W - 1);
        const int cb1 = min(max(cx + 1, 0), W - 1);
        const float mx0 = ((unsigned)cx       < (unsigned)W) ? 1.0f : 0.0f;
        const float mx1 = ((unsigned)(cx + 1) < (unsigned)W) ? 1.0f : 0.0f;
        const bool  strip = tid < 52;

        float wy0[5], wy1[5]; int yb0[5], yb1[5];
#pragma unroll
        for (int yy = 0; yy < 5; ++yy) {
            int yr = y0i + 4 * (yy - 2);
            wy0[yy] = ((unsigned)yr       < (unsigned)H) ? (1.0f - fy) : 0.0f;
            wy1[yy] = ((unsigned)(yr + 1) < (unsigned)H) ? fy          : 0.0f;
            yb0[yy] = min(max(yr, 0), H - 1) * W;
            yb1[yy] = min(max(yr + 1, 0), H - 1) * W;
        }

        const bool lw = tid < 100;         // 4 channels x 25 taps
        int lcc = 0, lb0 = 0, lb1 = 0, la0 = 0, la1 = 0, lidx = 0;
        float lmx0 = 0, lmx1 = 0, lwy0 = 0, lwy1 = 0;
        if (lw) {
            lcc = tid / 25;
            int w = tid - lcc * 25;
            int lyy = w / 5, lxx = w - lyy * 5;
            int lx = x0i + 4 * (lxx - 2);
            int ly = y0i + 4 * (lyy - 2);
            la0 = min(max(lx, 0), W - 1);
            la1 = min(max(lx + 1, 0), W - 1);
            lb0 = min(max(ly, 0), H - 1) * W;
            lb1 = min(max(ly + 1, 0), H - 1) * W;
            lmx0 = ((unsigned)lx       < (unsigned)W) ? 1.f : 0.f;
            lmx1 = ((unsigned)(lx + 1) < (unsigned)W) ? 1.f : 0.f;
            lwy0 = ((unsigned)ly       < (unsigned)H) ? (1.f - fy) : 0.f;
            lwy1 = ((unsigned)(ly + 1) < (unsigned)H) ? fy : 0.f;
            lidx = (lcc * 5 + lyy) * 8 + lxx;
        }

        float acc4 = 0.0f;
        for (int q = 0; q < 4; ++q) {
            const float* Rq = rfeat + (size_t)(lvl * NCH + 4 * q) * HW;
            const float* Lq = lfeat + (size_t)(lvl * NCH + 4 * q) * HW;
            if (strip) {
#pragma unroll 1
                for (int cc = 0; cc < 4; ++cc) {
                    const float* Rp = Rq + (size_t)cc * HW;
#pragma unroll
                    for (int yy = 0; yy < 5; ++yy) {
                        float v00 = Rp[yb0[yy] + cb0] * mx0, v01 = Rp[yb0[yy] + cb1] * mx1;
                        float v10 = Rp[yb1[yy] + cb0] * mx0, v11 = Rp[yb1[yy] + cb1] * mx1;
                        float top = v00 + fx * (v01 - v00);
                        float bot = v10 + fx * (v11 - v10);
                        svbuf[(cc * 5 + yy) * 56 + tid] = top * wy0[yy] + bot * wy1[yy];
                    }
                }
            }
            if (lw) {
                const float* Lp = Lq + (size_t)lcc * HW;
                float v00 = Lp[lb0 + la0] * lmx0, v01 = Lp[lb0 + la1] * lmx1;
                float v10 = Lp[lb1 + la0] * lmx0, v11 = Lp[lb1 + la1] * lmx1;
                float top = v00 + fx * (v01 - v00);
                float bot = v10 + fx * (v11 - v10);
                slbuf[lidx] = top * lwy0 + bot * lwy1;
            }
            __syncthreads();
            if (dl < 48) {
                const int base = 47 - dl;
                float aE = 0.f, aO = 0.f;
#pragma unroll
                for (int yy = 0; yy < 5; ++yy) {
                    const float* svp = &svbuf[(wv * 5 + yy) * 56 + base];
                    const float* slp = &slbuf[(wv * 5 + yy) * 8];
                    float t0 = fabsf(slp[0] - svp[0]);
                    float t1 = fabsf(slp[1] - svp[1]);
                    float t2 = fabsf(slp[2] - svp[2]);
                    float t3 = fabsf(slp[3] - svp[3]);
                    float t4 = fabsf(slp[4] - svp[4]);
                    aE += t0 + t2 + t4;
                    aO += t1 + t3;
                }
                acc4 += aE + aO;
            }
            __syncthreads();
        }
        if (dl < 48) part4[wv][dl] = acc4;
        __syncthreads();
        if (tid < 48) {
            float s4 = part4[0][tid] + part4[1][tid] + part4[2][tid] + part4[3][tid];
            val4[tid] = 1.0f - expf(-s4 * (1.0f / 400.0f));
        }
        // val4 ordered before epilogue by pass1's barriers; svbuf/slbuf reuse safe.
    }

    // =============== PASS 1: scale 1, D=192, level j, CG=2 ===============
    {
        const int lvl = j;
        const int cx  = x0i + tid - 193;
        const int cb0 = min(max(cx, 0), W - 1);
        const int cb1 = min(max(cx + 1, 0), W - 1);
        const float mx0 = ((unsigned)cx       < (unsigned)W) ? 1.0f : 0.0f;
        const float mx1 = ((unsigned)(cx + 1) < (unsigned)W) ? 1.0f : 0.0f;
        const bool  strip = tid < 196;

        float wy0[5], wy1[5]; int yb0[5], yb1[5];
#pragma unroll
        for (int yy = 0; yy < 5; ++yy) {
            int yr = y0i + (yy - 2);
            wy0[yy] = ((unsigned)yr       < (unsigned)H) ? (1.0f - fy) : 0.0f;
            wy1[yy] = ((unsigned)(yr + 1) < (unsigned)H) ? fy          : 0.0f;
            yb0[yy] = min(max(yr, 0), H - 1) * W;
            yb1[yy] = min(max(yr + 1, 0), H - 1) * W;
        }

        const bool lw = tid < 50;          // 2 channels x 25 taps
        int lcc = 0, lb0 = 0, lb1 = 0, la0 = 0, la1 = 0, lidx = 0;
        float lmx0 = 0, lmx1 = 0, lwy0 = 0, lwy1 = 0;
        if (lw) {
            lcc = tid / 25;
            int w = tid - lcc * 25;
            int lyy = w / 5, lxx = w - lyy * 5;
            int lx = x0i + (lxx - 2);
            int ly = y0i + (lyy - 2);
            la0 = min(max(lx, 0), W - 1);
            la1 = min(max(lx + 1, 0), W - 1);
            lb0 = min(max(ly, 0), H - 1) * W;
            lb1 = min(max(ly + 1, 0), H - 1) * W;
            lmx0 = ((unsigned)lx       < (unsigned)W) ? 1.f : 0.f;
            lmx1 = ((unsigned)(lx + 1) < (unsigned)W) ? 1.f : 0.f;
            lwy0 = ((unsigned)ly       < (unsigned)H) ? (1.f - fy) : 0.f;
            lwy1 = ((unsigned)(ly + 1) < (unsigned)H) ? fy : 0.f;
            lidx = (lcc * 5 + lyy) * 8 + lxx;
        }

        for (int q = 0; q < 8; ++q) {
            const float* Rq = rfeat + (size_t)(lvl * NCH + 2 * q) * HW;
            const float* Lq = lfeat + (size_t)(lvl * NCH + 2 * q) * HW;
            if (strip) {
#pragma unroll 1
                for (int cc = 0; cc < 2; ++cc) {
                    const float* Rp = Rq + (size_t)cc * HW;
#pragma unroll
                    for (int yy = 0; yy < 5; ++yy) {
                        float v00 = Rp[yb0[yy] + cb0] * mx0, v01 = Rp[yb0[yy] + cb1] * mx1;
                        float v10 = Rp[yb1[yy] + cb0] * mx0, v11 = Rp[yb1[yy] + cb1] * mx1;
                        float top = v00 + fx * (v01 - v00);
                        float bot = v10 + fx * (v11 - v10);
                        svbuf[(cc * 5 + yy) * 200 + tid] = top * wy0[yy] + bot * wy1[yy];
                    }
                }
            }
            if (lw) {
                const float* Lp = Lq + (size_t)lcc * HW;
                float v00 = Lp[lb0 + la0] * lmx0, v01 = Lp[lb0 + la1] * lmx1;
                float v10 = Lp[lb1 + la0] * lmx0, v11 = Lp[lb1 + la1] * lmx1;
                float top = v00 + fx * (v01 - v00);
                float bot = v10 + fx * (v11 - v10);
                slbuf[lidx] = top * lwy0 + bot * lwy1;
            }
            __syncthreads();
            if (tid < 192) {
                const int base = 191 - tid;
                float a0 = 0.f, a1 = 0.f;
#pragma unroll
                for (int yy = 0; yy < 5; ++yy) {
                    const float* sv0 = &svbuf[yy * 200 + base];
                    const float* sl0 = &slbuf[yy * 8];
                    const float* sv1 = &svbuf[(5 + yy) * 200 + base];
                    const float* sl1 = &slbuf[(5 + yy) * 8];
                    a0 += fabsf(sl0[0] - sv0[0]) + fabsf(sl0[1] - sv0[1])
                        + fabsf(sl0[2] - sv0[2]) + fabsf(sl0[3] - sv0[3])
                        + fabsf(sl0[4] - sv0[4]);
                    a1 += fabsf(sl1[0] - sv1[0]) + fabsf(sl1[1] - sv1[1])
                        + fabsf(sl1[2] - sv1[2]) + fabsf(sl1[3] - sv1[3])
                        + fabsf(sl1[4] - sv1[4]);
                }
                acc1 += a0 + a1;
            }
            __syncthreads();
        }
    }

    // =============== epilogue: upsample 48->192 and write ===============
    if (tid < MAXD) {
        float v1  = 1.0f - expf(-acc1 * (1.0f / 400.0f));
        float pos = (float)tid * (47.0f / 191.0f);
        float i0f = floorf(pos);
        int   i0  = (int)i0f;
        float w   = pos - i0f;
        int   i1  = min(i0 + 1, 47);
        float up  = val4[i0] + w * (val4[i1] - val4[i0]);
        out[((size_t)n * MAXD + tid) * 8 + j] = v1 + up;
    }
}

extern "C" void kernel_launch(void* const* d_in, const int* in_sizes, int n_in,
                              void* d_out, int out_size, void* d_ws, size_t ws_size,
                              hipStream_t stream) {
    const float* lf  = (const float*)d_in[0];
    const float* rf  = (const float*)d_in[1];
    const float* pts = (const float*)d_in[2];
    const int*   pW  = (const int*)d_in[3];
    const int*   pH  = (const int*)d_in[4];
    float* out = (float*)d_out;

    const int N = in_sizes[2] / 2;   // (B=1, N, 2)
    dim3 grid(N, 8, 1);
    pbm_kernel<<<grid, 256, 0, stream>>>(lf, rf, pts, pW, pH, out);
}

// Round 4
// 334.637 us; speedup vs baseline: 3.6605x; 1.6626x over previous
//
#include <hip/hip_runtime.h>

#define MAXD 192
#define NCH  16

__device__ __forceinline__ float samp(const float* __restrict__ p,
                                      int yb0, int yb1, float wy0, float wy1,
                                      int xb0, int xb1, float mxx0, float mxx1,
                                      float fx) {
    float v00 = p[yb0 + xb0] * mxx0, v01 = p[yb0 + xb1] * mxx1;
    float v10 = p[yb1 + xb0] * mxx0, v11 = p[yb1 + xb1] * mxx1;
    float top = v00 + fx * (v01 - v00);
    float bot = v10 + fx * (v11 - v10);
    return top * wy0 + bot * wy1;
}

#define RFL_I(x) __builtin_amdgcn_readfirstlane(x)
#define RFL_F(x) __int_as_float(__builtin_amdgcn_readfirstlane(__float_as_int(x)))
#define LDS_FENCE() do { asm volatile("s_waitcnt lgkmcnt(0)" ::: "memory"); \
                         __builtin_amdgcn_sched_barrier(0); } while (0)

// One block per (point n, level j). Waves 0-2: pass-1 (scale 1) disparity
// chunks [0,64),[64,128),[128,192). Wave 3: pass-0 (scale 4, D=48).
// Each wave stages its private LDS strip; no inter-wave barriers except the
// final val4 handoff. Bilinear frac weights/masks are block constants.
__global__ __launch_bounds__(256, 8) void pbm_kernel(
    const float* __restrict__ lfeat,   // (16,1,16,H,W)
    const float* __restrict__ rfeat,
    const float* __restrict__ points,  // (1,N,2)
    const int* __restrict__ pW, const int* __restrict__ pH,
    float* __restrict__ out)           // (1,N,192,8)
{
    const int W = RFL_I(*pW), H = RFL_I(*pH);
    const int HW = W * H;
    const int bid = blockIdx.x;
    const int j   = bid & 7;           // j == dispatch%8 -> same XCD L2 per level pair
    const int n   = bid >> 3;
    const int tid = threadIdx.x;
    const int wv  = tid >> 6;
    const int l   = tid & 63;

    const float pxr = points[2 * n];
    const float pyr = points[2 * n + 1];
    const float pxf = floorf(pxr), pyf = floorf(pyr);
    const float fx  = RFL_F(pxr - pxf);
    const float fy  = RFL_F(pyr - pyf);
    const int   x0i = RFL_I((int)pxf);
    const int   y0i = RFL_I((int)pyf);

    __shared__ float sv[4][5][68];     // per-wave right strip
    __shared__ float sl[4][25];        // per-wave left 5x5 window
    __shared__ float val4[48];

    // per-wave params (wave-uniform -> SGPR)
    const bool p0     = (wv == 3);
    const int  s_     = RFL_I(p0 ? 4 : 1);
    const int  lvl    = RFL_I(p0 ? j + 8 : j);
    const int  off    = RFL_I(p0 ? 49 : wv * 64 + 65);
    const int  DC     = RFL_I(p0 ? 48 : 64);
    const int  stageN = RFL_I(p0 ? 52 : 64);
    const int  clnN   = RFL_I(p0 ? 0 : 20);

    // strip column constants: col index == lane, offset o = s_*(l - off)
    const int   cx  = x0i + s_ * (l - off);
    const int   cb0 = min(max(cx, 0), W - 1);
    const int   cb1 = min(max(cx + 1, 0), W - 1);
    const float mx0 = ((unsigned)cx       < (unsigned)W) ? 1.0f : 0.0f;
    const float mx1 = ((unsigned)(cx + 1) < (unsigned)W) ? 1.0f : 0.0f;

    // cleanup taps (pass-1 waves): cols 64..67, rows l>>2, lanes 0..19
    const int   dyy = l >> 2;
    const int   dcol = 64 + (l & 3);
    const int   dcx = x0i + s_ * (dcol - off);
    const int   db0 = min(max(dcx, 0), W - 1);
    const int   db1 = min(max(dcx + 1, 0), W - 1);
    const float dmx0 = ((unsigned)dcx       < (unsigned)W) ? 1.0f : 0.0f;
    const float dmx1 = ((unsigned)(dcx + 1) < (unsigned)W) ? 1.0f : 0.0f;
    const int   dyr = y0i + s_ * (dyy - 2);
    const int   dyb0 = min(max(dyr, 0), H - 1) * W;
    const int   dyb1 = min(max(dyr + 1, 0), H - 1) * W;
    const float dwy0 = ((unsigned)dyr       < (unsigned)H) ? (1.0f - fy) : 0.0f;
    const float dwy1 = ((unsigned)(dyr + 1) < (unsigned)H) ? fy : 0.0f;

    // left-window taps: lanes 0..24, (lyy,lxx)
    const int   lyy = l / 5;
    const int   lxx = l - lyy * 5;
    const int   lx  = x0i + s_ * (lxx - 2);
    const int   ly  = y0i + s_ * (lyy - 2);
    const int   la0 = min(max(lx, 0), W - 1);
    const int   la1 = min(max(lx + 1, 0), W - 1);
    const float lmx0 = ((unsigned)lx       < (unsigned)W) ? 1.0f : 0.0f;
    const float lmx1 = ((unsigned)(lx + 1) < (unsigned)W) ? 1.0f : 0.0f;
    const int   lyb0 = min(max(ly, 0), H - 1) * W;
    const int   lyb1 = min(max(ly + 1, 0), H - 1) * W;
    const float lwy0 = ((unsigned)ly       < (unsigned)H) ? (1.0f - fy) : 0.0f;
    const float lwy1 = ((unsigned)(ly + 1) < (unsigned)H) ? fy : 0.0f;

    const float* Rb = rfeat + (size_t)(lvl * NCH) * HW;
    const float* Lb = lfeat + (size_t)(lvl * NCH) * HW;

    float acc = 0.0f;
#pragma unroll 1
    for (int c = 0; c < NCH; ++c) {
        const float* Rp = Rb + (size_t)c * HW;
        const float* Lp = Lb + (size_t)c * HW;

        if (l < stageN) {
#pragma unroll 1
            for (int yy = 0; yy < 5; ++yy) {
                int   yr  = y0i + s_ * (yy - 2);          // scalar math
                int   yb0 = min(max(yr, 0), H - 1) * W;
                int   yb1 = min(max(yr + 1, 0), H - 1) * W;
                float wy0 = ((unsigned)yr       < (unsigned)H) ? (1.0f - fy) : 0.0f;
                float wy1 = ((unsigned)(yr + 1) < (unsigned)H) ? fy : 0.0f;
                sv[wv][yy][l] = samp(Rp, yb0, yb1, wy0, wy1, cb0, cb1, mx0, mx1, fx);
            }
        }
        if (l < clnN)
            sv[wv][dyy][dcol] = samp(Rp, dyb0, dyb1, dwy0, dwy1, db0, db1, dmx0, dmx1, fx);
        if (l < 25)
            sl[wv][l] = samp(Lp, lyb0, lyb1, lwy0, lwy1, la0, la1, lmx0, lmx1, fx);

        LDS_FENCE();                    // wave-internal write->read ordering

        if (l < DC) {
            const float* svp = &sv[wv][0][DC - 1 - l];
            const float* slp = &sl[wv][0];
            float a0 = 0.f, a1 = 0.f;
#pragma unroll
            for (int yy = 0; yy < 5; ++yy) {
                a0 += fabsf(slp[yy * 5 + 0] - svp[yy * 68 + 0]);
                a1 += fabsf(slp[yy * 5 + 1] - svp[yy * 68 + 1]);
                a0 += fabsf(slp[yy * 5 + 2] - svp[yy * 68 + 2]);
                a1 += fabsf(slp[yy * 5 + 3] - svp[yy * 68 + 3]);
                a0 += fabsf(slp[yy * 5 + 4] - svp[yy * 68 + 4]);
            }
            acc += a0 + a1;
        }

        LDS_FENCE();                    // read->next-write ordering
    }

    if (p0 && l < 48)
        val4[l] = 1.0f - expf(-acc * (1.0f / 400.0f));

    __syncthreads();                    // the ONLY block-wide barrier

    if (tid < MAXD) {                   // waves 0-2: d == tid
        float v1  = 1.0f - expf(-acc * (1.0f / 400.0f));
        float pos = (float)tid * (47.0f / 191.0f);
        float i0f = floorf(pos);
        int   i0  = (int)i0f;
        float w   = pos - i0f;
        int   i1  = min(i0 + 1, 47);
        float up  = val4[i0] + w * (val4[i1] - val4[i0]);
        out[((size_t)n * MAXD + tid) * 8 + j] = v1 + up;
    }
}

extern "C" void kernel_launch(void* const* d_in, const int* in_sizes, int n_in,
                              void* d_out, int out_size, void* d_ws, size_t ws_size,
                              hipStream_t stream) {
    const float* lf  = (const float*)d_in[0];
    const float* rf  = (const float*)d_in[1];
    const float* pts = (const float*)d_in[2];
    const int*   pW  = (const int*)d_in[3];
    const int*   pH  = (const int*)d_in[4];
    float* out = (float*)d_out;

    const int N = in_sizes[2] / 2;     // (B=1, N, 2)
    pbm_kernel<<<dim3(N * 8), 256, 0, stream>>>(lf, rf, pts, pW, pH, out);
}